// Round 13
// baseline (2923.475 us; speedup 1.0000x reference)
//
#include <hip/hip_runtime.h>
#include <hip/hip_bf16.h>
#include <math.h>

// ---- static problem geometry ----
#define Bb   2
#define Hh   5
#define NTT  16
#define NPP  256
#define NWW  64
#define NRR  1
#define PTT  321                 // NPP+NWW+NRR
#define SS   1621                // NTT + Hh*PTT
#define SSP  1664                // SS padded to 64 (VTg row stride)
#define DINN 512
#define DD   768
#define NHH  12
#define DHH  64
#define LL   12
#define DFF  3072
#define MM   3242                // Bb*SS
#define MPAD 3328                // 52*64 = 26*128
#define QKVN 2304                // 3*DD
#define EROWS 3232               // 32 task + 2560 prim + 640 wrist rows of [512]

typedef __hip_bfloat16 bf16;
typedef _Float16 f16;
typedef __attribute__((ext_vector_type(4))) float  f32x4;
typedef __attribute__((ext_vector_type(8))) __bf16 bf16x8;
typedef __attribute__((ext_vector_type(8))) _Float16 f16x8;

// bijective XCD swizzle (m204): each XCD gets a contiguous block range
__device__ __forceinline__ int xcd_swz(int id, int nwg) {
  int q = nwg >> 3, r = nwg & 7;
  int xcd = id & 7, idx = id >> 3;
  return (xcd < r ? xcd * (q + 1) : r * (q + 1) + (xcd - r) * q) + idx;
}

// group id / timestep from flat sequence index
__device__ __forceinline__ void gid_ts(int i, int& g, int& t) {
  if (i < NTT) { g = 0; t = -1; }
  else {
    int j = i - NTT;
    t = j / PTT;
    int r = j - t * PTT;
    g = (r < NPP) ? 1 : ((r < NPP + NWW) ? 2 : 3);
  }
}

// ========== bf16 MFMA GEMM, 64x64 tile (for N=768 GEMMs: O-proj, W2, embeds) ==========
template<int ACT, int RES, int OUTBF, int QKVMODE>
__global__ __launch_bounds__(256) void gemm64_k(
    const bf16* __restrict__ A, const bf16* __restrict__ BT,
    const float* __restrict__ bias, const float* __restrict__ Rs,
    void* __restrict__ Cout, f16* __restrict__ VTg,
    int M, int N, int K)
{
  __shared__ bf16 Al[2][64 * 64];
  __shared__ bf16 Bl[2][64 * 64];
  const int tid = threadIdx.x;
  const int lane = tid & 63, w = tid >> 6;
  const int wr = w >> 1, wc = w & 1;
  int bxi, byi;
  {
    const int nwg = gridDim.x * gridDim.y;
    int swz = xcd_swz(blockIdx.y * gridDim.x + blockIdx.x, nwg);
    bxi = swz % gridDim.x; byi = swz / gridDim.x;
  }
  const int bm = byi * 64, bn = bxi * 64;
  const int r0 = lane & 15, kg4 = lane >> 4;
  f32x4 acc[2][2] = {};

  auto STAGE = [&](int s, int k0) {
    #pragma unroll
    for (int i = 0; i < 2; ++i) {
      int chunk = i * 256 + tid;           // 512 16B-chunks per operand tile
      int row = chunk >> 3, c8 = chunk & 7;
      const bf16* ga = A  + (size_t)(bm + row) * K + (k0 + c8 * 8);
      const bf16* gb = BT + (size_t)(bn + row) * K + (k0 + c8 * 8);
      __builtin_amdgcn_global_load_lds(
          (const __attribute__((address_space(1))) void*)ga,
          (__attribute__((address_space(3))) void*)((char*)Al[s] + chunk * 16), 16, 0, 0);
      __builtin_amdgcn_global_load_lds(
          (const __attribute__((address_space(1))) void*)gb,
          (__attribute__((address_space(3))) void*)((char*)Bl[s] + chunk * 16), 16, 0, 0);
    }
  };

  const int nt = K >> 6;
  STAGE(0, 0);
  __syncthreads();
  int cur = 0;
  for (int t = 0; t < nt; ++t) {
    if (t + 1 < nt) STAGE(cur ^ 1, (t + 1) << 6);   // prefetch next tile
    #pragma unroll
    for (int ks = 0; ks < 2; ++ks) {
      bf16x8 af[2], bfr[2];
      const int koff = ks * 32 + kg4 * 8;
      #pragma unroll
      for (int mi = 0; mi < 2; ++mi)
        af[mi] = *(const bf16x8*)((const void*)(Al[cur] + (wr * 32 + mi * 16 + r0) * 64 + koff));
      #pragma unroll
      for (int ni = 0; ni < 2; ++ni)
        bfr[ni] = *(const bf16x8*)((const void*)(Bl[cur] + (wc * 32 + ni * 16 + r0) * 64 + koff));
      #pragma unroll
      for (int mi = 0; mi < 2; ++mi)
        #pragma unroll
        for (int ni = 0; ni < 2; ++ni)
          acc[mi][ni] = __builtin_amdgcn_mfma_f32_16x16x32_bf16(af[mi], bfr[ni], acc[mi][ni], 0, 0, 0);
    }
    __syncthreads();
    cur ^= 1;
  }
  #pragma unroll
  for (int mi = 0; mi < 2; ++mi) {
    #pragma unroll
    for (int ni = 0; ni < 2; ++ni) {
      const int gcol = bn + wc * 32 + ni * 16 + r0;
      const float bv = bias[gcol];
      const int gr0 = bm + wr * 32 + mi * 16 + kg4 * 4;
      #pragma unroll
      for (int j = 0; j < 4; ++j) {
        const int gm = gr0 + j;
        if (gm >= M) continue;
        float vv = acc[mi][ni][j] + bv;
        if (ACT == 1) {
          float xx = vv;
          float th = tanhf(0.7978845608028654f * (xx + 0.044715f * xx * xx * xx));
          vv = 0.5f * xx * (1.f + th);
        }
        if (RES) vv += Rs[(size_t)gm * N + gcol];
        if (QKVMODE && gcol >= 1536) {
          const int vc = gcol - 1536;
          const int hh = vc >> 6, d = vc & 63;
          const int bb = gm >= SS;
          const int s = gm - bb * SS;
          VTg[(size_t)((bb * NHH + hh) * 64 + d) * SSP + s] = (f16)vv;
        } else if (OUTBF) {
          ((bf16*)Cout)[(size_t)gm * N + gcol] = __float2bfloat16(vv);
        } else {
          ((float*)Cout)[(size_t)gm * N + gcol] = vv;
        }
      }
    }
  }
}

// ========== bf16 MFMA GEMM, 128x128 tile (QKV N=2304, W1 N=3072) ==========
// m97 structure: 4 waves (2x2 quadrants of 64x64), 4x4 frags/wave, BK=64,
// double-buffered LDS (64 KB), prefetch-before-compute, bijective XCD swizzle.
// 2x compute-per-staged-byte vs 64^2 -- use where grid >= ~1.8 blocks/CU.
template<int ACT, int RES, int OUTBF, int QKVMODE>
__global__ __launch_bounds__(256) void gemm128_k(
    const bf16* __restrict__ A, const bf16* __restrict__ BT,
    const float* __restrict__ bias, const float* __restrict__ Rs,
    void* __restrict__ Cout, f16* __restrict__ VTg,
    int M, int N, int K)
{
  __shared__ bf16 Al[2][128 * 64];
  __shared__ bf16 Bl[2][128 * 64];
  const int tid = threadIdx.x;
  const int lane = tid & 63, w = tid >> 6;
  const int wr = w >> 1, wc = w & 1;
  int bxi, byi;
  {
    const int nwg = gridDim.x * gridDim.y;
    int swz = xcd_swz(blockIdx.y * gridDim.x + blockIdx.x, nwg);
    bxi = swz % gridDim.x; byi = swz / gridDim.x;
  }
  const int bm = byi * 128, bn = bxi * 128;
  const int r0 = lane & 15, kg4 = lane >> 4;
  const int cb = w * 4;
  f32x4 acc[4][4] = {};

  auto STAGE = [&](int s, int k0) {
    #pragma unroll
    for (int i = 0; i < 4; ++i) {
      int chunk = (cb + i) * 64 + lane;    // 1024 16B-chunks per operand tile
      int row = chunk >> 3, c8 = chunk & 7;
      const bf16* ga = A  + (size_t)(bm + row) * K + (k0 + c8 * 8);
      const bf16* gb = BT + (size_t)(bn + row) * K + (k0 + c8 * 8);
      __builtin_amdgcn_global_load_lds(
          (const __attribute__((address_space(1))) void*)ga,
          (__attribute__((address_space(3))) void*)((char*)Al[s] + chunk * 16), 16, 0, 0);
      __builtin_amdgcn_global_load_lds(
          (const __attribute__((address_space(1))) void*)gb,
          (__attribute__((address_space(3))) void*)((char*)Bl[s] + chunk * 16), 16, 0, 0);
    }
  };

  const int nt = K >> 6;
  STAGE(0, 0);
  __syncthreads();
  int cur = 0;
  for (int t = 0; t < nt; ++t) {
    if (t + 1 < nt) STAGE(cur ^ 1, (t + 1) << 6);   // prefetch next tile
    #pragma unroll
    for (int ks = 0; ks < 2; ++ks) {
      bf16x8 af[4], bfr[4];
      const int koff = ks * 32 + kg4 * 8;
      #pragma unroll
      for (int mi = 0; mi < 4; ++mi)
        af[mi] = *(const bf16x8*)((const void*)(Al[cur] + (wr * 64 + mi * 16 + r0) * 64 + koff));
      #pragma unroll
      for (int ni = 0; ni < 4; ++ni)
        bfr[ni] = *(const bf16x8*)((const void*)(Bl[cur] + (wc * 64 + ni * 16 + r0) * 64 + koff));
      #pragma unroll
      for (int mi = 0; mi < 4; ++mi)
        #pragma unroll
        for (int ni = 0; ni < 4; ++ni)
          acc[mi][ni] = __builtin_amdgcn_mfma_f32_16x16x32_bf16(af[mi], bfr[ni], acc[mi][ni], 0, 0, 0);
    }
    __syncthreads();
    cur ^= 1;
  }
  #pragma unroll
  for (int mi = 0; mi < 4; ++mi) {
    #pragma unroll
    for (int ni = 0; ni < 4; ++ni) {
      const int gcol = bn + wc * 64 + ni * 16 + r0;
      const float bv = bias[gcol];
      const int gr0 = bm + wr * 64 + mi * 16 + kg4 * 4;
      #pragma unroll
      for (int j = 0; j < 4; ++j) {
        const int gm = gr0 + j;
        if (gm >= M) continue;
        float vv = acc[mi][ni][j] + bv;
        if (ACT == 1) {
          float xx = vv;
          float th = tanhf(0.7978845608028654f * (xx + 0.044715f * xx * xx * xx));
          vv = 0.5f * xx * (1.f + th);
        }
        if (RES) vv += Rs[(size_t)gm * N + gcol];
        if (QKVMODE && gcol >= 1536) {
          const int vc = gcol - 1536;
          const int hh = vc >> 6, d = vc & 63;
          const int bb = gm >= SS;
          const int s = gm - bb * SS;
          VTg[(size_t)((bb * NHH + hh) * 64 + d) * SSP + s] = (f16)vv;
        } else if (OUTBF) {
          ((bf16*)Cout)[(size_t)gm * N + gcol] = __float2bfloat16(vv);
        } else {
          ((float*)Cout)[(size_t)gm * N + gcol] = vv;
        }
      }
    }
  }
}

// ---------------- LayerNorm (fp32 in, bf16 or f32 out) ----------------
template<int OUTBF>
__global__ __launch_bounds__(256) void ln2_k(
    const float* __restrict__ X, const float* __restrict__ sc,
    const float* __restrict__ bi, void* __restrict__ Y)
{
  const int row = blockIdx.x;
  const float* x = X + (size_t)row * DD;
  const int t = threadIdx.x;
  float v0 = x[t], v1 = x[t + 256], v2 = x[t + 512];
  float sum = v0 + v1 + v2;
  const int lane = t & 63, wid = t >> 6;
  __shared__ float rs[4];
  #pragma unroll
  for (int o = 32; o; o >>= 1) sum += __shfl_xor(sum, o);
  if (lane == 0) rs[wid] = sum;
  __syncthreads();
  float mean = (rs[0] + rs[1] + rs[2] + rs[3]) * (1.f / DD);
  __syncthreads();
  float d0 = v0 - mean, d1 = v1 - mean, d2 = v2 - mean;
  float sq = d0 * d0 + d1 * d1 + d2 * d2;
  #pragma unroll
  for (int o = 32; o; o >>= 1) sq += __shfl_xor(sq, o);
  if (lane == 0) rs[wid] = sq;
  __syncthreads();
  float var = (rs[0] + rs[1] + rs[2] + rs[3]) * (1.f / DD);
  float inv = rsqrtf(var + 1e-6f);
  float o0 = d0 * inv * sc[t] + bi[t];
  float o1 = d1 * inv * sc[t + 256] + bi[t + 256];
  float o2 = d2 * inv * sc[t + 512] + bi[t + 512];
  if (OUTBF) {
    bf16* y = (bf16*)Y + (size_t)row * DD;
    y[t] = __float2bfloat16(o0); y[t + 256] = __float2bfloat16(o1); y[t + 512] = __float2bfloat16(o2);
  } else {
    float* y = (float*)Y + (size_t)row * DD;
    y[t] = o0; y[t + 256] = o1; y[t + 512] = o2;
  }
}

// ================= MFMA flash attention (double-buffered K/V staging) =======
__global__ __launch_bounds__(256) void mattn_k(
    const bf16* __restrict__ qkv, const f16* __restrict__ VTg,
    bf16* __restrict__ ao, const unsigned char* __restrict__ kflags)
{
  __shared__ bf16 Kl[2][64 * 64];         // [ktok][dh], dh-chunks XOR-swizzled
  __shared__ f16  Vl[2][64 * 64];         // [d][kv], kv-chunks XOR-swizzled
  __shared__ unsigned short Pl[4][16][72];// per-wave P [q][k] fp16, pad 72
  __shared__ unsigned char Fl[2][64];
  const int tid = threadIdx.x;
  const int lane = tid & 63, w = tid >> 6;
  const int r0 = lane & 15, g = lane >> 4;
  // decode swizzled 1D block id: 624 = 26 qt x 12 h x 2 b, qt fastest
  int swz;
  {
    int id = blockIdx.x;
    swz = (id & 7) * 78 + (id >> 3);      // 624/8 = 78
  }
  const int qt = swz % 26;
  const int hb = swz / 26;
  const int h = hb % NHH, b = hb / NHH;

  const int q_my = qt * 64 + w * 16 + r0;     // this lane's q (S^T column)
  const int qc = min(q_my, SS - 1);
  int gq, tq; gid_ts(qc, gq, tq);
  const int kend = (tq < 0) ? NTT : NTT + (tq + 1) * PTT;
  const bool gq3 = (gq == 3);

  const int qlast = min(qt * 64 + 63, SS - 1);
  int gl, tl; gid_ts(qlast, gl, tl);
  const int kend_b = (tl < 0) ? NTT : NTT + (tl + 1) * PTT;
  const int ntiles = (kend_b + 63) >> 6;

  // Q fragments: Q[qc][ks*32 + g*8 .. +8]
  bf16x8 qf[2];
  {
    const bf16* qrow = qkv + (size_t)(b * SS + qc) * QKVN + h * DHH;
    qf[0] = *(const bf16x8*)((const void*)(qrow + g * 8));
    qf[1] = *(const bf16x8*)((const void*)(qrow + 32 + g * 8));
  }

  auto STAGE = [&](int s, int kt) {
    const int kv0 = kt * 64;
    #pragma unroll
    for (int i = 0; i < 2; ++i) {
      int c = i * 256 + tid;
      int row = c >> 3, blk = c & 7;
      int srow = min(kv0 + row, SS - 1);
      const bf16* srcK = qkv + (size_t)(b * SS + srow) * QKVN + DD + h * DHH + ((blk ^ (row & 7)) * 8);
      __builtin_amdgcn_global_load_lds(
          (const __attribute__((address_space(1))) void*)srcK,
          (__attribute__((address_space(3))) void*)((char*)Kl[s] + c * 16), 16, 0, 0);
      int kvs = kv0 + ((blk ^ (row & 7)) * 8);   // VTg pad cols [SS,SSP) zeroed
      const f16* srcV = VTg + (size_t)((b * NHH + h) * 64 + row) * SSP + kvs;
      __builtin_amdgcn_global_load_lds(
          (const __attribute__((address_space(1))) void*)srcV,
          (__attribute__((address_space(3))) void*)((char*)Vl[s] + c * 16), 16, 0, 0);
    }
    if (tid < 64) Fl[s][tid] = kflags[b * SS + min(kv0 + tid, SS - 1)];
  };

  f32x4 o_acc[4] = {};   // O C/D: col d = n*16+r0, row q = g*4+j
  float l_run = 0.f;

  STAGE(0, 0);
  __syncthreads();
  int cur = 0;
  for (int kt = 0; kt < ntiles; ++kt) {
    const int kv0 = kt * 64;
    if (kt + 1 < ntiles) STAGE(cur ^ 1, kt + 1);   // prefetch next K/V tile

    // S^T = K @ Q^T  (A = K rows from Kl swizzled, B^T rows = Q rows = qf)
    f32x4 st[4] = {};
    #pragma unroll
    for (int ks = 0; ks < 2; ++ks) {
      #pragma unroll
      for (int t = 0; t < 4; ++t) {
        const int krow = t * 16 + r0;
        const bf16x8 af = *(const bf16x8*)((const void*)(
            (char*)Kl[cur] + krow * 128 + ((ks * 64 + g * 16) ^ ((krow & 7) << 4))));
        st[t] = __builtin_amdgcn_mfma_f32_16x16x32_bf16(af, qf[ks], st[t], 0, 0, 0);
      }
    }
    // mask + exp + write P in fp16 (lane's q = r0 within wave)
    #pragma unroll
    for (int t = 0; t < 4; ++t) {
      const unsigned fl4 = *(const unsigned*)((const void*)&Fl[cur][t * 16 + g * 4]);
      unsigned short pk[4];
      #pragma unroll
      for (int r = 0; r < 4; ++r) {
        const int kg_ = kv0 + t * 16 + g * 4 + r;
        const unsigned fb = (fl4 >> (8 * r)) & 0xffu;
        const bool ok = (kg_ < kend) && (fb & 1) && (gq3 || !(fb & 2));
        float ee = fminf(fmaf(st[t][r], 0.125f, -2.0f), 10.0f);
        float pv = ok ? __expf(ee) : 0.f;
        f16 hb2 = (f16)pv;
        l_run += (float)hb2;   // denominator matches quantized numerator
        pk[r] = *(unsigned short*)&hb2;
      }
      uint2 pw;
      pw.x = (unsigned)pk[0] | ((unsigned)pk[1] << 16);
      pw.y = (unsigned)pk[2] | ((unsigned)pk[3] << 16);
      *(uint2*)((void*)&Pl[w][r0][t * 16 + g * 4]) = pw;
    }
    // P ds_writes -> visible to this wave's ds_reads; keep prefetch vmcnt alive
    asm volatile("s_waitcnt lgkmcnt(0)" ::: "memory");
    __builtin_amdgcn_sched_barrier(0);
    // PV: O += P @ V   (A = P rows from Pl fp16, B^T rows = VT rows from Vl)
    #pragma unroll
    for (int ks = 0; ks < 2; ++ks) {
      const f16x8 pa = *(const f16x8*)((const void*)(
          (char*)&Pl[w][r0][0] + ks * 64 + g * 16));
      #pragma unroll
      for (int n = 0; n < 4; ++n) {
        const int drow = n * 16 + r0;
        const f16x8 bv = *(const f16x8*)((const void*)(
            (char*)Vl[cur] + drow * 128 + ((ks * 64 + g * 16) ^ ((drow & 7) << 4))));
        o_acc[n] = __builtin_amdgcn_mfma_f32_16x16x32_f16(pa, bv, o_acc[n], 0, 0, 0);
      }
    }
    __syncthreads();   // drains prefetch + all waves done with cur
    cur ^= 1;
  }
  // denominator: lane's q total = sum over g-groups
  float lt = l_run;
  lt += __shfl_xor(lt, 16);
  lt += __shfl_xor(lt, 32);
  const float inv = 1.f / lt;
  float invr[4];
  #pragma unroll
  for (int j = 0; j < 4; ++j) invr[j] = __shfl(inv, g * 4 + j);
  // write O rows
  #pragma unroll
  for (int n = 0; n < 4; ++n) {
    const int d = n * 16 + r0;
    #pragma unroll
    for (int j = 0; j < 4; ++j) {
      const int q = qt * 64 + w * 16 + g * 4 + j;
      if (q < SS)
        ao[(size_t)(b * SS + q) * DD + h * DHH + d] = __float2bfloat16(o_acc[n][j] * invr[j]);
    }
  }
}

// ---------------- token assembly ----------------
__global__ __launch_bounds__(256) void assemble_k(
    const float* __restrict__ tE, const float* __restrict__ pE, const float* __restrict__ wE,
    const float* __restrict__ posT, const float* __restrict__ posP,
    const float* __restrict__ posW, const float* __restrict__ posR,
    float* __restrict__ X)
{
  const int row = blockIdx.x;
  const int b = row / SS, s = row - b * SS;
  float* x = X + (size_t)row * DD;
  const float* src; const float* pos;
  if (s < NTT) { src = tE + (size_t)(b * NTT + s) * DD; pos = posT + (size_t)s * DD; }
  else {
    int j = s - NTT, t = j / PTT, r = j - t * PTT;
    if (r < NPP)            { src = pE + (size_t)((b * Hh + t) * NPP + r) * DD;
                              pos = posP + (size_t)(t * NPP + r) * DD; }
    else if (r < NPP + NWW) { src = wE + (size_t)((b * Hh + t) * NWW + (r - NPP)) * DD;
                              pos = posW + (size_t)(t * NWW + (r - NPP)) * DD; }
    else                    { src = nullptr; pos = posR + (size_t)t * DD; }
  }
  for (int d = threadIdx.x; d < DD; d += 256)
    x[d] = (src ? src[d] : 0.f) + pos[d];
}

// key flags: bit0 = key valid (pad_mask), bit1 = is readout column
__global__ void build_kv_k(const void* pm, unsigned char* kvout) {
  int i = blockIdx.x * 256 + threadIdx.x;
  if (i >= Bb * SS) return;
  int b = i / SS, s = i - b * SS;
  int g, t; gid_ts(s, g, t);
  unsigned char valid = 1;
  if (g == 1 || g == 2) {
    int idx = b * Hh + t;
    unsigned char c = ((const unsigned char*)pm)[idx];
    int ii = ((const int*)pm)[idx];
    valid = (c != 0 || ii != 0) ? 1 : 0;
  }
  kvout[i] = valid | ((g == 3) ? 2 : 0);
}

// zero a buffer (16B granules)
__global__ void zset_k(ushort4* p, int n16) {
  int i = blockIdx.x * 256 + threadIdx.x;
  if (i < n16) { ushort4 z = {0, 0, 0, 0}; p[i] = z; }
}

// ---- embed weight transpose+convert: W[512][768] f32 -> ET[sel][768][512] bf16 ----
__global__ __launch_bounds__(256) void eprep_k(
    const float* __restrict__ Wt, const float* __restrict__ Wp, const float* __restrict__ Ww,
    bf16* __restrict__ ET)
{
  const int bid = blockIdx.x;          // 3 * 16 * 24 = 1152
  const int sel = bid / 384, rem = bid % 384;
  const int a = rem / 24, bcol = rem % 24;
  const float* src = sel == 0 ? Wt : (sel == 1 ? Wp : Ww);
  bf16* dst = ET + (size_t)sel * 768 * 512;
  __shared__ float t[32][33];
  const int ib = threadIdx.x >> 5, j = threadIdx.x & 31;
  #pragma unroll
  for (int rr = 0; rr < 4; ++rr) {
    int i = ib + rr * 8;
    t[i][j] = src[(size_t)(a * 32 + i) * 768 + bcol * 32 + j];
  }
  __syncthreads();
  #pragma unroll
  for (int rr = 0; rr < 4; ++rr) {
    int i = ib + rr * 8;
    dst[(size_t)(bcol * 32 + i) * 512 + a * 32 + j] = __float2bfloat16(t[j][i]);
  }
}

// ---- convert embed inputs f32 -> bf16 rows [EROWS][512] ----
__global__ void cvtA_k(const float* __restrict__ t, const float* __restrict__ p,
                       const float* __restrict__ w, bf16* __restrict__ out)
{
  int i = blockIdx.x * 256 + threadIdx.x;   // one float4 per thread
  const int total4 = EROWS * 512 / 4;
  if (i >= total4) return;
  int e = i * 4;
  const float* src; int off;
  if (e < 32 * 512)        { src = t; off = e; }
  else if (e < 2592 * 512) { src = p; off = e - 32 * 512; }
  else                     { src = w; off = e - 2592 * 512; }
  float4 v = *(const float4*)(src + off);
  bf16* o = out + e;
  o[0] = __float2bfloat16(v.x); o[1] = __float2bfloat16(v.y);
  o[2] = __float2bfloat16(v.z); o[3] = __float2bfloat16(v.w);
}

// ---- ALL layers weight transpose+convert, one launch, 64x64 tiles ----
__global__ __launch_bounds__(256) void prep12_k(
    const float* __restrict__ Wq, const float* __restrict__ Wk, const float* __restrict__ Wv,
    const float* __restrict__ Wo, const float* __restrict__ W1, const float* __restrict__ W2,
    bf16* __restrict__ QKVT, bf16* __restrict__ OT,
    bf16* __restrict__ W1T, bf16* __restrict__ W2T,
    const float* __restrict__ bq_, const float* __restrict__ bk_,
    const float* __restrict__ bv_, float* __restrict__ bqkv)
{
  const int l = blockIdx.x / 1729;
  const int bid = blockIdx.x % 1729;
  if (bid == 1728) {  // bias concat tail
    int i = threadIdx.x;
    for (; i < QKVN; i += 256) {
      float v = (i < DD) ? bq_[l * DD + i]
              : ((i < 2 * DD) ? bk_[l * DD + i - DD] : bv_[l * DD + i - 2 * DD]);
      bqkv[l * QKVN + i] = v;
    }
    return;
  }
  __shared__ float t[64][65];
  const float* src; bf16* dst;
  int a, bcol, R, C, dbase;
  if (bid < 432)       { int sel = bid / 144, rem = bid % 144; a = rem / 12; bcol = rem % 12;
                         src = (sel == 0 ? Wq : (sel == 1 ? Wk : Wv)) + (size_t)l * DD * DD;
                         dst = QKVT + (size_t)l * QKVN * DD; R = 768; C = 768; dbase = sel * 768; }
  else if (bid < 576)  { int rem = bid - 432; a = rem / 12; bcol = rem % 12;
                         src = Wo + (size_t)l * DD * DD; dst = OT + (size_t)l * DD * DD;
                         R = 768; C = 768; dbase = 0; }
  else if (bid < 1152) { int rem = bid - 576; a = rem / 48; bcol = rem % 48;
                         src = W1 + (size_t)l * DD * DFF; dst = W1T + (size_t)l * DFF * DD;
                         R = 768; C = 3072; dbase = 0; }
  else                 { int rem = bid - 1152; a = rem / 12; bcol = rem % 12;
                         src = W2 + (size_t)l * DFF * DD; dst = W2T + (size_t)l * DD * DFF;
                         R = 3072; C = 768; dbase = 0; }
  const int ib = threadIdx.x >> 6, j = threadIdx.x & 63;
  #pragma unroll
  for (int rr = 0; rr < 16; ++rr) {
    int i = rr * 4 + ib;
    t[i][j] = src[(size_t)(a * 64 + i) * C + bcol * 64 + j];
  }
  __syncthreads();
  #pragma unroll
  for (int rr = 0; rr < 16; ++rr) {
    int i = rr * 4 + ib;
    dst[(size_t)(dbase + bcol * 64 + i) * R + a * 64 + j] = __float2bfloat16(t[j][i]);
  }
}

extern "C" void kernel_launch(void* const* d_in, const int* in_sizes, int n_in,
                              void* d_out, int out_size, void* d_ws, size_t ws_size,
                              hipStream_t stream)
{
  const float* task_tokens = (const float*)d_in[0];
  const float* obs_primary = (const float*)d_in[1];
  const float* obs_wrist   = (const float*)d_in[2];
  const float* W_task      = (const float*)d_in[3];
  const float* b_task      = (const float*)d_in[4];
  const float* W_primary   = (const float*)d_in[5];
  const float* b_primary   = (const float*)d_in[6];
  const float* W_wrist     = (const float*)d_in[7];
  const float* b_wrist     = (const float*)d_in[8];
  const float* pos_task    = (const float*)d_in[9];
  const float* pos_primary = (const float*)d_in[10];
  const float* pos_wrist   = (const float*)d_in[11];
  const float* pos_readout = (const float*)d_in[12];
  const float* ln1_s = (const float*)d_in[13];
  const float* ln1_b = (const float*)d_in[14];
  const float* Wq = (const float*)d_in[15];
  const float* bq = (const float*)d_in[16];
  const float* Wk = (const float*)d_in[17];
  const float* bk = (const float*)d_in[18];
  const float* Wv = (const float*)d_in[19];
  const float* bv = (const float*)d_in[20];
  const float* Wo = (const float*)d_in[21];
  const float* bo = (const float*)d_in[22];
  const float* ln2_s = (const float*)d_in[23];
  const float* ln2_b = (const float*)d_in[24];
  const float* W1 = (const float*)d_in[25];
  const float* b1 = (const float*)d_in[26];
  const float* W2 = (const float*)d_in[27];
  const float* b2 = (const float*)d_in[28];
  const float* lnf_s = (const float*)d_in[29];
  const float* lnf_b = (const float*)d_in[30];
  const void*  pad_mask = d_in[31];

  // ---- workspace layout ----
  char* p = (char*)d_ws;
  auto alloc = [&](size_t bytes) { char* r = p; p += (bytes + 255) & ~(size_t)255; return r; };
  float* x    = (float*)alloc((size_t)MPAD * DD * 4);
  bf16*  y    = (bf16*) alloc((size_t)MPAD * DD * 2);
  bf16*  qkv  = (bf16*) alloc((size_t)MPAD * QKVN * 2);
  bf16*  ao   = (bf16*) alloc((size_t)MPAD * DD * 2);
  f16*   VTg  = (f16*)  alloc((size_t)Bb * NHH * 64 * SSP * 2);
  bf16*  QKVT = (bf16*) alloc((size_t)LL * QKVN * DD * 2);
  bf16*  OT   = (bf16*) alloc((size_t)LL * DD * DD * 2);
  bf16*  W1T  = (bf16*) alloc((size_t)LL * DFF * DD * 2);
  bf16*  W2T  = (bf16*) alloc((size_t)LL * DD * DFF * 2);
  bf16*  ET   = (bf16*) alloc((size_t)3 * DD * DINN * 2);
  bf16*  abf  = (bf16*) alloc((size_t)EROWS * DINN * 2);
  float* bqkv = (float*)alloc((size_t)LL * QKVN * 4);
  unsigned char* keyv = (unsigned char*)alloc(Bb * SS);
  // union region: {h1} | {te,pe,we}
  char* uni = alloc((size_t)MPAD * DFF * 2);
  bf16*  h1   = (bf16*)uni;
  float* te   = (float*)uni;
  float* pe   = te + (size_t)Bb * NTT * DD;
  float* we   = pe + (size_t)Bb * Hh * NPP * DD;

  // --- one-time setup ---
  {
    int n16 = (int)((size_t)Bb * NHH * 64 * SSP * 2 / 16);
    zset_k<<<dim3((n16 + 255) / 256), 256, 0, stream>>>((ushort4*)VTg, n16);  // zero pad cols
  }
  prep12_k<<<LL * 1729, 256, 0, stream>>>(Wq, Wk, Wv, Wo, W1, W2,
                                          QKVT, OT, W1T, W2T, bq, bk, bv, bqkv);
  eprep_k<<<1152, 256, 0, stream>>>(W_task, W_primary, W_wrist, ET);
  cvtA_k<<<dim3((EROWS * 512 / 4 + 255) / 256), 256, 0, stream>>>(
      task_tokens, obs_primary, obs_wrist, abf);
  gemm64_k<0, 0, 0, 0><<<dim3(12, 1),  256, 0, stream>>>(
      abf,               ET,                 b_task,    nullptr, te, nullptr, 32,   DD, DINN);
  gemm64_k<0, 0, 0, 0><<<dim3(12, 40), 256, 0, stream>>>(
      abf + 32 * DINN,   ET + DD * DINN,     b_primary, nullptr, pe, nullptr, 2560, DD, DINN);
  gemm64_k<0, 0, 0, 0><<<dim3(12, 10), 256, 0, stream>>>(
      abf + 2592 * DINN, ET + 2 * DD * DINN, b_wrist,   nullptr, we, nullptr, 640,  DD, DINN);
  assemble_k<<<dim3(MM), 256, 0, stream>>>(te, pe, we, pos_task, pos_primary, pos_wrist, pos_readout, x);
  build_kv_k<<<dim3((Bb * SS + 255) / 256), 256, 0, stream>>>(pad_mask, keyv);

  // --- transformer layers ---
  for (int l = 0; l < LL; ++l) {
    ln2_k<1><<<MM, 256, 0, stream>>>(x, ln1_s + l * DD, ln1_b + l * DD, y);
    // fused QKV gemm (128^2 tile): QK cols -> qkv, V cols -> VTg (fp16 transposed)
    gemm128_k<0, 0, 1, 1><<<dim3(QKVN / 128, MPAD / 128), 256, 0, stream>>>(
        y, QKVT + (size_t)l * QKVN * DD, bqkv + l * QKVN, nullptr, qkv, VTg, MM, QKVN, DD);
    mattn_k<<<dim3(26 * NHH * Bb), 256, 0, stream>>>(qkv, VTg, ao, keyv);
    gemm64_k<0, 1, 0, 0><<<dim3(DD / 64, MPAD / 64), 256, 0, stream>>>(
        ao, OT + (size_t)l * DD * DD, bo + l * DD, x, x, nullptr, MM, DD, DD);
    ln2_k<1><<<MM, 256, 0, stream>>>(x, ln2_s + l * DD, ln2_b + l * DD, y);
    // W1 gemm (128^2 tile) + GELU
    gemm128_k<1, 0, 1, 0><<<dim3(DFF / 128, MPAD / 128), 256, 0, stream>>>(
        y, W1T + (size_t)l * DFF * DD, b1 + l * DFF, nullptr, h1, nullptr, MM, DFF, DD);
    gemm64_k<0, 1, 0, 0><<<dim3(DD / 64, MPAD / 64), 256, 0, stream>>>(
        h1, W2T + (size_t)l * DD * DFF, b2 + l * DD, x, x, nullptr, MM, DD, DFF);
  }
  // --- final LN -> d_out ---
  ln2_k<0><<<MM, 256, 0, stream>>>(x, lnf_s, lnf_b, d_out);
}

// Round 14
// 2750.170 us; speedup vs baseline: 1.0630x; 1.0630x over previous
//
#include <hip/hip_runtime.h>
#include <hip/hip_bf16.h>
#include <math.h>

// ---- static problem geometry ----
#define Bb   2
#define Hh   5
#define NTT  16
#define NPP  256
#define NWW  64
#define NRR  1
#define PTT  321                 // NPP+NWW+NRR
#define SS   1621                // NTT + Hh*PTT
#define SSP  1664                // SS padded to 64 (VTg row stride)
#define DINN 512
#define DD   768
#define NHH  12
#define DHH  64
#define LL   12
#define DFF  3072
#define MM   3242                // Bb*SS
#define MPAD 3328                // 52*64
#define QKVN 2304                // 3*DD
#define EROWS 3232               // 32 task + 2560 prim + 640 wrist rows of [512]

typedef __hip_bfloat16 bf16;
typedef _Float16 f16;
typedef __attribute__((ext_vector_type(4))) float  f32x4;
typedef __attribute__((ext_vector_type(8))) __bf16 bf16x8;
typedef __attribute__((ext_vector_type(8))) _Float16 f16x8;

// bijective XCD swizzle (m204): each XCD gets a contiguous block range
__device__ __forceinline__ int xcd_swz(int id, int nwg) {
  int q = nwg >> 3, r = nwg & 7;
  int xcd = id & 7, idx = id >> 3;
  return (xcd < r ? xcd * (q + 1) : r * (q + 1) + (xcd - r) * q) + idx;
}

// group id / timestep from flat sequence index
__device__ __forceinline__ void gid_ts(int i, int& g, int& t) {
  if (i < NTT) { g = 0; t = -1; }
  else {
    int j = i - NTT;
    t = j / PTT;
    int r = j - t * PTT;
    g = (r < NPP) ? 1 : ((r < NPP + NWW) ? 2 : 3);
  }
}

// ========== bf16 MFMA GEMM, 64x64 tile (ALL layer GEMMs + embeds) ==========
// 4 waves (2x2 quadrants of 32x32), BK=64, double-buffered LDS (32 KB),
// prefetch-issue-before-compute, bijective XCD swizzle. R13 showed 128^2
// tiles LOSE here (64KB LDS halves blocks/CU; grids too small to refill).
// QKVMODE=1: cols >=1536 (V range) are written TRANSPOSED fp16 to VTg.
template<int ACT, int RES, int OUTBF, int QKVMODE>
__global__ __launch_bounds__(256) void gemm64_k(
    const bf16* __restrict__ A, const bf16* __restrict__ BT,
    const float* __restrict__ bias, const float* __restrict__ Rs,
    void* __restrict__ Cout, f16* __restrict__ VTg,
    int M, int N, int K)
{
  __shared__ bf16 Al[2][64 * 64];
  __shared__ bf16 Bl[2][64 * 64];
  const int tid = threadIdx.x;
  const int lane = tid & 63, w = tid >> 6;
  const int wr = w >> 1, wc = w & 1;
  int bxi, byi;
  {
    const int nwg = gridDim.x * gridDim.y;
    int swz = xcd_swz(blockIdx.y * gridDim.x + blockIdx.x, nwg);
    bxi = swz % gridDim.x; byi = swz / gridDim.x;
  }
  const int bm = byi * 64, bn = bxi * 64;
  const int r0 = lane & 15, kg4 = lane >> 4;
  f32x4 acc[2][2] = {};

  auto STAGE = [&](int s, int k0) {
    #pragma unroll
    for (int i = 0; i < 2; ++i) {
      int chunk = i * 256 + tid;           // 512 16B-chunks per operand tile
      int row = chunk >> 3, c8 = chunk & 7;
      const bf16* ga = A  + (size_t)(bm + row) * K + (k0 + c8 * 8);
      const bf16* gb = BT + (size_t)(bn + row) * K + (k0 + c8 * 8);
      __builtin_amdgcn_global_load_lds(
          (const __attribute__((address_space(1))) void*)ga,
          (__attribute__((address_space(3))) void*)((char*)Al[s] + chunk * 16), 16, 0, 0);
      __builtin_amdgcn_global_load_lds(
          (const __attribute__((address_space(1))) void*)gb,
          (__attribute__((address_space(3))) void*)((char*)Bl[s] + chunk * 16), 16, 0, 0);
    }
  };

  const int nt = K >> 6;
  STAGE(0, 0);
  __syncthreads();
  int cur = 0;
  for (int t = 0; t < nt; ++t) {
    if (t + 1 < nt) STAGE(cur ^ 1, (t + 1) << 6);   // prefetch next tile
    #pragma unroll
    for (int ks = 0; ks < 2; ++ks) {
      bf16x8 af[2], bfr[2];
      const int koff = ks * 32 + kg4 * 8;
      #pragma unroll
      for (int mi = 0; mi < 2; ++mi)
        af[mi] = *(const bf16x8*)((const void*)(Al[cur] + (wr * 32 + mi * 16 + r0) * 64 + koff));
      #pragma unroll
      for (int ni = 0; ni < 2; ++ni)
        bfr[ni] = *(const bf16x8*)((const void*)(Bl[cur] + (wc * 32 + ni * 16 + r0) * 64 + koff));
      #pragma unroll
      for (int mi = 0; mi < 2; ++mi)
        #pragma unroll
        for (int ni = 0; ni < 2; ++ni)
          acc[mi][ni] = __builtin_amdgcn_mfma_f32_16x16x32_bf16(af[mi], bfr[ni], acc[mi][ni], 0, 0, 0);
    }
    __syncthreads();
    cur ^= 1;
  }
  // epilogue: C/D layout col=lane&15, row=(lane>>4)*4+reg
  #pragma unroll
  for (int mi = 0; mi < 2; ++mi) {
    #pragma unroll
    for (int ni = 0; ni < 2; ++ni) {
      const int gcol = bn + wc * 32 + ni * 16 + r0;
      const float bv = bias[gcol];
      const int gr0 = bm + wr * 32 + mi * 16 + kg4 * 4;
      #pragma unroll
      for (int j = 0; j < 4; ++j) {
        const int gm = gr0 + j;
        if (gm >= M) continue;
        float vv = acc[mi][ni][j] + bv;
        if (ACT == 1) {
          float xx = vv;
          float th = tanhf(0.7978845608028654f * (xx + 0.044715f * xx * xx * xx));
          vv = 0.5f * xx * (1.f + th);
        }
        if (RES) vv += Rs[(size_t)gm * N + gcol];
        if (QKVMODE && gcol >= 1536) {
          const int vc = gcol - 1536;
          const int hh = vc >> 6, d = vc & 63;
          const int bb = gm >= SS;
          const int s = gm - bb * SS;
          VTg[(size_t)((bb * NHH + hh) * 64 + d) * SSP + s] = (f16)vv;
        } else if (OUTBF) {
          ((bf16*)Cout)[(size_t)gm * N + gcol] = __float2bfloat16(vv);
        } else {
          ((float*)Cout)[(size_t)gm * N + gcol] = vv;
        }
      }
    }
  }
}

// ---------------- LayerNorm (fp32 in, bf16 or f32 out) ----------------
template<int OUTBF>
__global__ __launch_bounds__(256) void ln2_k(
    const float* __restrict__ X, const float* __restrict__ sc,
    const float* __restrict__ bi, void* __restrict__ Y)
{
  const int row = blockIdx.x;
  const float* x = X + (size_t)row * DD;
  const int t = threadIdx.x;
  float v0 = x[t], v1 = x[t + 256], v2 = x[t + 512];
  float sum = v0 + v1 + v2;
  const int lane = t & 63, wid = t >> 6;
  __shared__ float rs[4];
  #pragma unroll
  for (int o = 32; o; o >>= 1) sum += __shfl_xor(sum, o);
  if (lane == 0) rs[wid] = sum;
  __syncthreads();
  float mean = (rs[0] + rs[1] + rs[2] + rs[3]) * (1.f / DD);
  __syncthreads();
  float d0 = v0 - mean, d1 = v1 - mean, d2 = v2 - mean;
  float sq = d0 * d0 + d1 * d1 + d2 * d2;
  #pragma unroll
  for (int o = 32; o; o >>= 1) sq += __shfl_xor(sq, o);
  if (lane == 0) rs[wid] = sq;
  __syncthreads();
  float var = (rs[0] + rs[1] + rs[2] + rs[3]) * (1.f / DD);
  float inv = rsqrtf(var + 1e-6f);
  float o0 = d0 * inv * sc[t] + bi[t];
  float o1 = d1 * inv * sc[t + 256] + bi[t + 256];
  float o2 = d2 * inv * sc[t + 512] + bi[t + 512];
  if (OUTBF) {
    bf16* y = (bf16*)Y + (size_t)row * DD;
    y[t] = __float2bfloat16(o0); y[t + 256] = __float2bfloat16(o1); y[t + 512] = __float2bfloat16(o2);
  } else {
    float* y = (float*)Y + (size_t)row * DD;
    y[t] = o0; y[t + 256] = o1; y[t + 512] = o2;
  }
}

// ================= MFMA flash attention (double-buffered K/V staging) =======
// 1D grid of 624 blocks, XCD-swizzled so each XCD owns ~3 (b,h) heads.
// 256 thr = 4 waves; block = 64 q-rows. Fixed softmax shift m=2 (clamped):
// P = exp(min(S/8-2, 10)) fp16; PV via mfma f16. T5: setprio(1) around the
// MFMA clusters (multi-wave block, phase-diverse -> scheduler can arbitrate).
__global__ __launch_bounds__(256) void mattn_k(
    const bf16* __restrict__ qkv, const f16* __restrict__ VTg,
    bf16* __restrict__ ao, const unsigned char* __restrict__ kflags)
{
  __shared__ bf16 Kl[2][64 * 64];         // [ktok][dh], dh-chunks XOR-swizzled
  __shared__ f16  Vl[2][64 * 64];         // [d][kv], kv-chunks XOR-swizzled
  __shared__ unsigned short Pl[4][16][72];// per-wave P [q][k] fp16, pad 72
  __shared__ unsigned char Fl[2][64];
  const int tid = threadIdx.x;
  const int lane = tid & 63, w = tid >> 6;
  const int r0 = lane & 15, g = lane >> 4;
  // decode swizzled 1D block id: 624 = 26 qt x 12 h x 2 b, qt fastest
  int swz;
  {
    int id = blockIdx.x;
    swz = (id & 7) * 78 + (id >> 3);      // 624/8 = 78
  }
  const int qt = swz % 26;
  const int hb = swz / 26;
  const int h = hb % NHH, b = hb / NHH;

  const int q_my = qt * 64 + w * 16 + r0;     // this lane's q (S^T column)
  const int qc = min(q_my, SS - 1);
  int gq, tq; gid_ts(qc, gq, tq);
  const int kend = (tq < 0) ? NTT : NTT + (tq + 1) * PTT;
  const bool gq3 = (gq == 3);

  const int qlast = min(qt * 64 + 63, SS - 1);
  int gl, tl; gid_ts(qlast, gl, tl);
  const int kend_b = (tl < 0) ? NTT : NTT + (tl + 1) * PTT;
  const int ntiles = (kend_b + 63) >> 6;

  // Q fragments: Q[qc][ks*32 + g*8 .. +8]
  bf16x8 qf[2];
  {
    const bf16* qrow = qkv + (size_t)(b * SS + qc) * QKVN + h * DHH;
    qf[0] = *(const bf16x8*)((const void*)(qrow + g * 8));
    qf[1] = *(const bf16x8*)((const void*)(qrow + 32 + g * 8));
  }

  auto STAGE = [&](int s, int kt) {
    const int kv0 = kt * 64;
    #pragma unroll
    for (int i = 0; i < 2; ++i) {
      int c = i * 256 + tid;
      int row = c >> 3, blk = c & 7;
      int srow = min(kv0 + row, SS - 1);
      const bf16* srcK = qkv + (size_t)(b * SS + srow) * QKVN + DD + h * DHH + ((blk ^ (row & 7)) * 8);
      __builtin_amdgcn_global_load_lds(
          (const __attribute__((address_space(1))) void*)srcK,
          (__attribute__((address_space(3))) void*)((char*)Kl[s] + c * 16), 16, 0, 0);
      int kvs = kv0 + ((blk ^ (row & 7)) * 8);   // VTg pad cols [SS,SSP) zeroed
      const f16* srcV = VTg + (size_t)((b * NHH + h) * 64 + row) * SSP + kvs;
      __builtin_amdgcn_global_load_lds(
          (const __attribute__((address_space(1))) void*)srcV,
          (__attribute__((address_space(3))) void*)((char*)Vl[s] + c * 16), 16, 0, 0);
    }
    if (tid < 64) Fl[s][tid] = kflags[b * SS + min(kv0 + tid, SS - 1)];
  };

  f32x4 o_acc[4] = {};   // O C/D: col d = n*16+r0, row q = g*4+j
  float l_run = 0.f;

  STAGE(0, 0);
  __syncthreads();
  int cur = 0;
  for (int kt = 0; kt < ntiles; ++kt) {
    const int kv0 = kt * 64;
    if (kt + 1 < ntiles) STAGE(cur ^ 1, kt + 1);   // prefetch next K/V tile

    // S^T = K @ Q^T  (A = K rows from Kl swizzled, B^T rows = Q rows = qf)
    f32x4 st[4] = {};
    __builtin_amdgcn_s_setprio(1);
    #pragma unroll
    for (int ks = 0; ks < 2; ++ks) {
      #pragma unroll
      for (int t = 0; t < 4; ++t) {
        const int krow = t * 16 + r0;
        const bf16x8 af = *(const bf16x8*)((const void*)(
            (char*)Kl[cur] + krow * 128 + ((ks * 64 + g * 16) ^ ((krow & 7) << 4))));
        st[t] = __builtin_amdgcn_mfma_f32_16x16x32_bf16(af, qf[ks], st[t], 0, 0, 0);
      }
    }
    __builtin_amdgcn_s_setprio(0);
    // mask + exp + write P in fp16 (lane's q = r0 within wave)
    #pragma unroll
    for (int t = 0; t < 4; ++t) {
      const unsigned fl4 = *(const unsigned*)((const void*)&Fl[cur][t * 16 + g * 4]);
      unsigned short pk[4];
      #pragma unroll
      for (int r = 0; r < 4; ++r) {
        const int kg_ = kv0 + t * 16 + g * 4 + r;
        const unsigned fb = (fl4 >> (8 * r)) & 0xffu;
        const bool ok = (kg_ < kend) && (fb & 1) && (gq3 || !(fb & 2));
        float ee = fminf(fmaf(st[t][r], 0.125f, -2.0f), 10.0f);
        float pv = ok ? __expf(ee) : 0.f;
        f16 hb2 = (f16)pv;
        l_run += (float)hb2;   // denominator matches quantized numerator
        pk[r] = *(unsigned short*)&hb2;
      }
      uint2 pw;
      pw.x = (unsigned)pk[0] | ((unsigned)pk[1] << 16);
      pw.y = (unsigned)pk[2] | ((unsigned)pk[3] << 16);
      *(uint2*)((void*)&Pl[w][r0][t * 16 + g * 4]) = pw;
    }
    // P ds_writes -> visible to this wave's ds_reads; keep prefetch vmcnt alive
    asm volatile("s_waitcnt lgkmcnt(0)" ::: "memory");
    __builtin_amdgcn_sched_barrier(0);
    // PV: O += P @ V   (A = P rows from Pl fp16, B^T rows = VT rows from Vl)
    __builtin_amdgcn_s_setprio(1);
    #pragma unroll
    for (int ks = 0; ks < 2; ++ks) {
      const f16x8 pa = *(const f16x8*)((const void*)(
          (char*)&Pl[w][r0][0] + ks * 64 + g * 16));
      #pragma unroll
      for (int n = 0; n < 4; ++n) {
        const int drow = n * 16 + r0;
        const f16x8 bv = *(const f16x8*)((const void*)(
            (char*)Vl[cur] + drow * 128 + ((ks * 64 + g * 16) ^ ((drow & 7) << 4))));
        o_acc[n] = __builtin_amdgcn_mfma_f32_16x16x32_f16(pa, bv, o_acc[n], 0, 0, 0);
      }
    }
    __builtin_amdgcn_s_setprio(0);
    __syncthreads();   // drains prefetch + all waves done with cur
    cur ^= 1;
  }
  // denominator: lane's q total = sum over g-groups
  float lt = l_run;
  lt += __shfl_xor(lt, 16);
  lt += __shfl_xor(lt, 32);
  const float inv = 1.f / lt;
  float invr[4];
  #pragma unroll
  for (int j = 0; j < 4; ++j) invr[j] = __shfl(inv, g * 4 + j);
  // write O rows
  #pragma unroll
  for (int n = 0; n < 4; ++n) {
    const int d = n * 16 + r0;
    #pragma unroll
    for (int j = 0; j < 4; ++j) {
      const int q = qt * 64 + w * 16 + g * 4 + j;
      if (q < SS)
        ao[(size_t)(b * SS + q) * DD + h * DHH + d] = __float2bfloat16(o_acc[n][j] * invr[j]);
    }
  }
}

// ---------------- token assembly ----------------
__global__ __launch_bounds__(256) void assemble_k(
    const float* __restrict__ tE, const float* __restrict__ pE, const float* __restrict__ wE,
    const float* __restrict__ posT, const float* __restrict__ posP,
    const float* __restrict__ posW, const float* __restrict__ posR,
    float* __restrict__ X)
{
  const int row = blockIdx.x;
  const int b = row / SS, s = row - b * SS;
  float* x = X + (size_t)row * DD;
  const float* src; const float* pos;
  if (s < NTT) { src = tE + (size_t)(b * NTT + s) * DD; pos = posT + (size_t)s * DD; }
  else {
    int j = s - NTT, t = j / PTT, r = j - t * PTT;
    if (r < NPP)            { src = pE + (size_t)((b * Hh + t) * NPP + r) * DD;
                              pos = posP + (size_t)(t * NPP + r) * DD; }
    else if (r < NPP + NWW) { src = wE + (size_t)((b * Hh + t) * NWW + (r - NPP)) * DD;
                              pos = posW + (size_t)(t * NWW + (r - NPP)) * DD; }
    else                    { src = nullptr; pos = posR + (size_t)t * DD; }
  }
  for (int d = threadIdx.x; d < DD; d += 256)
    x[d] = (src ? src[d] : 0.f) + pos[d];
}

// key flags: bit0 = key valid (pad_mask), bit1 = is readout column
__global__ void build_kv_k(const void* pm, unsigned char* kvout) {
  int i = blockIdx.x * 256 + threadIdx.x;
  if (i >= Bb * SS) return;
  int b = i / SS, s = i - b * SS;
  int g, t; gid_ts(s, g, t);
  unsigned char valid = 1;
  if (g == 1 || g == 2) {
    int idx = b * Hh + t;
    unsigned char c = ((const unsigned char*)pm)[idx];
    int ii = ((const int*)pm)[idx];
    valid = (c != 0 || ii != 0) ? 1 : 0;
  }
  kvout[i] = valid | ((g == 3) ? 2 : 0);
}

// zero a buffer (16B granules)
__global__ void zset_k(ushort4* p, int n16) {
  int i = blockIdx.x * 256 + threadIdx.x;
  if (i < n16) { ushort4 z = {0, 0, 0, 0}; p[i] = z; }
}

// ---- embed weight transpose+convert: W[512][768] f32 -> ET[sel][768][512] bf16 ----
__global__ __launch_bounds__(256) void eprep_k(
    const float* __restrict__ Wt, const float* __restrict__ Wp, const float* __restrict__ Ww,
    bf16* __restrict__ ET)
{
  const int bid = blockIdx.x;          // 3 * 16 * 24 = 1152
  const int sel = bid / 384, rem = bid % 384;
  const int a = rem / 24, bcol = rem % 24;
  const float* src = sel == 0 ? Wt : (sel == 1 ? Wp : Ww);
  bf16* dst = ET + (size_t)sel * 768 * 512;
  __shared__ float t[32][33];
  const int ib = threadIdx.x >> 5, j = threadIdx.x & 31;
  #pragma unroll
  for (int rr = 0; rr < 4; ++rr) {
    int i = ib + rr * 8;
    t[i][j] = src[(size_t)(a * 32 + i) * 768 + bcol * 32 + j];
  }
  __syncthreads();
  #pragma unroll
  for (int rr = 0; rr < 4; ++rr) {
    int i = ib + rr * 8;
    dst[(size_t)(bcol * 32 + i) * 512 + a * 32 + j] = __float2bfloat16(t[j][i]);
  }
}

// ---- convert embed inputs f32 -> bf16 rows [EROWS][512] ----
__global__ void cvtA_k(const float* __restrict__ t, const float* __restrict__ p,
                       const float* __restrict__ w, bf16* __restrict__ out)
{
  int i = blockIdx.x * 256 + threadIdx.x;   // one float4 per thread
  const int total4 = EROWS * 512 / 4;
  if (i >= total4) return;
  int e = i * 4;
  const float* src; int off;
  if (e < 32 * 512)        { src = t; off = e; }
  else if (e < 2592 * 512) { src = p; off = e - 32 * 512; }
  else                     { src = w; off = e - 2592 * 512; }
  float4 v = *(const float4*)(src + off);
  bf16* o = out + e;
  o[0] = __float2bfloat16(v.x); o[1] = __float2bfloat16(v.y);
  o[2] = __float2bfloat16(v.z); o[3] = __float2bfloat16(v.w);
}

// ---- ALL layers weight transpose+convert, one launch, 64x64 tiles ----
__global__ __launch_bounds__(256) void prep12_k(
    const float* __restrict__ Wq, const float* __restrict__ Wk, const float* __restrict__ Wv,
    const float* __restrict__ Wo, const float* __restrict__ W1, const float* __restrict__ W2,
    bf16* __restrict__ QKVT, bf16* __restrict__ OT,
    bf16* __restrict__ W1T, bf16* __restrict__ W2T,
    const float* __restrict__ bq_, const float* __restrict__ bk_,
    const float* __restrict__ bv_, float* __restrict__ bqkv)
{
  const int l = blockIdx.x / 1729;
  const int bid = blockIdx.x % 1729;
  if (bid == 1728) {  // bias concat tail
    int i = threadIdx.x;
    for (; i < QKVN; i += 256) {
      float v = (i < DD) ? bq_[l * DD + i]
              : ((i < 2 * DD) ? bk_[l * DD + i - DD] : bv_[l * DD + i - 2 * DD]);
      bqkv[l * QKVN + i] = v;
    }
    return;
  }
  __shared__ float t[64][65];
  const float* src; bf16* dst;
  int a, bcol, R, C, dbase;
  if (bid < 432)       { int sel = bid / 144, rem = bid % 144; a = rem / 12; bcol = rem % 12;
                         src = (sel == 0 ? Wq : (sel == 1 ? Wk : Wv)) + (size_t)l * DD * DD;
                         dst = QKVT + (size_t)l * QKVN * DD; R = 768; C = 768; dbase = sel * 768; }
  else if (bid < 576)  { int rem = bid - 432; a = rem / 12; bcol = rem % 12;
                         src = Wo + (size_t)l * DD * DD; dst = OT + (size_t)l * DD * DD;
                         R = 768; C = 768; dbase = 0; }
  else if (bid < 1152) { int rem = bid - 576; a = rem / 48; bcol = rem % 48;
                         src = W1 + (size_t)l * DD * DFF; dst = W1T + (size_t)l * DFF * DD;
                         R = 768; C = 3072; dbase = 0; }
  else                 { int rem = bid - 1152; a = rem / 12; bcol = rem % 12;
                         src = W2 + (size_t)l * DFF * DD; dst = W2T + (size_t)l * DD * DFF;
                         R = 3072; C = 768; dbase = 0; }
  const int ib = threadIdx.x >> 6, j = threadIdx.x & 63;
  #pragma unroll
  for (int rr = 0; rr < 16; ++rr) {
    int i = rr * 4 + ib;
    t[i][j] = src[(size_t)(a * 64 + i) * C + bcol * 64 + j];
  }
  __syncthreads();
  #pragma unroll
  for (int rr = 0; rr < 16; ++rr) {
    int i = rr * 4 + ib;
    dst[(size_t)(dbase + bcol * 64 + i) * R + a * 64 + j] = __float2bfloat16(t[j][i]);
  }
}

extern "C" void kernel_launch(void* const* d_in, const int* in_sizes, int n_in,
                              void* d_out, int out_size, void* d_ws, size_t ws_size,
                              hipStream_t stream)
{
  const float* task_tokens = (const float*)d_in[0];
  const float* obs_primary = (const float*)d_in[1];
  const float* obs_wrist   = (const float*)d_in[2];
  const float* W_task      = (const float*)d_in[3];
  const float* b_task      = (const float*)d_in[4];
  const float* W_primary   = (const float*)d_in[5];
  const float* b_primary   = (const float*)d_in[6];
  const float* W_wrist     = (const float*)d_in[7];
  const float* b_wrist     = (const float*)d_in[8];
  const float* pos_task    = (const float*)d_in[9];
  const float* pos_primary = (const float*)d_in[10];
  const float* pos_wrist   = (const float*)d_in[11];
  const float* pos_readout = (const float*)d_in[12];
  const float* ln1_s = (const float*)d_in[13];
  const float* ln1_b = (const float*)d_in[14];
  const float* Wq = (const float*)d_in[15];
  const float* bq = (const float*)d_in[16];
  const float* Wk = (const float*)d_in[17];
  const float* bk = (const float*)d_in[18];
  const float* Wv = (const float*)d_in[19];
  const float* bv = (const float*)d_in[20];
  const float* Wo = (const float*)d_in[21];
  const float* bo = (const float*)d_in[22];
  const float* ln2_s = (const float*)d_in[23];
  const float* ln2_b = (const float*)d_in[24];
  const float* W1 = (const float*)d_in[25];
  const float* b1 = (const float*)d_in[26];
  const float* W2 = (const float*)d_in[27];
  const float* b2 = (const float*)d_in[28];
  const float* lnf_s = (const float*)d_in[29];
  const float* lnf_b = (const float*)d_in[30];
  const void*  pad_mask = d_in[31];

  // ---- workspace layout ----
  char* p = (char*)d_ws;
  auto alloc = [&](size_t bytes) { char* r = p; p += (bytes + 255) & ~(size_t)255; return r; };
  float* x    = (float*)alloc((size_t)MPAD * DD * 4);
  bf16*  y    = (bf16*) alloc((size_t)MPAD * DD * 2);
  bf16*  qkv  = (bf16*) alloc((size_t)MPAD * QKVN * 2);
  bf16*  ao   = (bf16*) alloc((size_t)MPAD * DD * 2);
  f16*   VTg  = (f16*)  alloc((size_t)Bb * NHH * 64 * SSP * 2);
  bf16*  QKVT = (bf16*) alloc((size_t)LL * QKVN * DD * 2);
  bf16*  OT   = (bf16*) alloc((size_t)LL * DD * DD * 2);
  bf16*  W1T  = (bf16*) alloc((size_t)LL * DFF * DD * 2);
  bf16*  W2T  = (bf16*) alloc((size_t)LL * DD * DFF * 2);
  bf16*  ET   = (bf16*) alloc((size_t)3 * DD * DINN * 2);
  bf16*  abf  = (bf16*) alloc((size_t)EROWS * DINN * 2);
  float* bqkv = (float*)alloc((size_t)LL * QKVN * 4);
  unsigned char* keyv = (unsigned char*)alloc(Bb * SS);
  // union region: {h1} | {te,pe,we}
  char* uni = alloc((size_t)MPAD * DFF * 2);
  bf16*  h1   = (bf16*)uni;
  float* te   = (float*)uni;
  float* pe   = te + (size_t)Bb * NTT * DD;
  float* we   = pe + (size_t)Bb * Hh * NPP * DD;

  // --- one-time setup ---
  {
    int n16 = (int)((size_t)Bb * NHH * 64 * SSP * 2 / 16);
    zset_k<<<dim3((n16 + 255) / 256), 256, 0, stream>>>((ushort4*)VTg, n16);  // zero pad cols
  }
  prep12_k<<<LL * 1729, 256, 0, stream>>>(Wq, Wk, Wv, Wo, W1, W2,
                                          QKVT, OT, W1T, W2T, bq, bk, bv, bqkv);
  eprep_k<<<1152, 256, 0, stream>>>(W_task, W_primary, W_wrist, ET);
  cvtA_k<<<dim3((EROWS * 512 / 4 + 255) / 256), 256, 0, stream>>>(
      task_tokens, obs_primary, obs_wrist, abf);
  gemm64_k<0, 0, 0, 0><<<dim3(12, 1),  256, 0, stream>>>(
      abf,               ET,                 b_task,    nullptr, te, nullptr, 32,   DD, DINN);
  gemm64_k<0, 0, 0, 0><<<dim3(12, 40), 256, 0, stream>>>(
      abf + 32 * DINN,   ET + DD * DINN,     b_primary, nullptr, pe, nullptr, 2560, DD, DINN);
  gemm64_k<0, 0, 0, 0><<<dim3(12, 10), 256, 0, stream>>>(
      abf + 2592 * DINN, ET + 2 * DD * DINN, b_wrist,   nullptr, we, nullptr, 640,  DD, DINN);
  assemble_k<<<dim3(MM), 256, 0, stream>>>(te, pe, we, pos_task, pos_primary, pos_wrist, pos_readout, x);
  build_kv_k<<<dim3((Bb * SS + 255) / 256), 256, 0, stream>>>(pad_mask, keyv);

  // --- transformer layers (all 64^2 tiles; R13 showed 128^2 regresses here) ---
  for (int l = 0; l < LL; ++l) {
    ln2_k<1><<<MM, 256, 0, stream>>>(x, ln1_s + l * DD, ln1_b + l * DD, y);
    // fused QKV gemm: QK cols -> qkv, V cols -> VTg (transposed fp16)
    gemm64_k<0, 0, 1, 1><<<dim3(QKVN / 64, MPAD / 64), 256, 0, stream>>>(
        y, QKVT + (size_t)l * QKVN * DD, bqkv + l * QKVN, nullptr, qkv, VTg, MM, QKVN, DD);
    mattn_k<<<dim3(26 * NHH * Bb), 256, 0, stream>>>(qkv, VTg, ao, keyv);
    gemm64_k<0, 1, 0, 0><<<dim3(DD / 64, MPAD / 64), 256, 0, stream>>>(
        ao, OT + (size_t)l * DD * DD, bo + l * DD, x, x, nullptr, MM, DD, DD);
    ln2_k<1><<<MM, 256, 0, stream>>>(x, ln2_s + l * DD, ln2_b + l * DD, y);
    gemm64_k<1, 0, 1, 0><<<dim3(DFF / 64, MPAD / 64), 256, 0, stream>>>(
        y, W1T + (size_t)l * DFF * DD, b1 + l * DFF, nullptr, h1, nullptr, MM, DFF, DD);
    gemm64_k<0, 1, 0, 0><<<dim3(DD / 64, MPAD / 64), 256, 0, stream>>>(
        h1, W2T + (size_t)l * DD * DFF, b2 + l * DD, x, x, nullptr, MM, DD, DFF);
  }
  // --- final LN -> d_out ---
  ln2_k<0><<<MM, 256, 0, stream>>>(x, lnf_s, lnf_b, d_out);
}

// Round 15
// 2736.535 us; speedup vs baseline: 1.0683x; 1.0050x over previous
//
#include <hip/hip_runtime.h>
#include <hip/hip_bf16.h>
#include <math.h>

// ---- static problem geometry ----
#define Bb   2
#define Hh   5
#define NTT  16
#define NPP  256
#define NWW  64
#define NRR  1
#define PTT  321                 // NPP+NWW+NRR
#define SS   1621                // NTT + Hh*PTT
#define SSP  1664                // SS padded to 64 (VTg row stride)
#define DINN 512
#define DD   768
#define NHH  12
#define DHH  64
#define LL   12
#define DFF  3072
#define MM   3242                // Bb*SS
#define MPAD 3328                // 52*64
#define QKVN 2304                // 3*DD
#define EROWS 3232               // 32 task + 2560 prim + 640 wrist rows of [512]
#define NKT  26                  // ceil(SS/64) k-tiles

typedef __hip_bfloat16 bf16;
typedef _Float16 f16;
typedef __attribute__((ext_vector_type(4))) float  f32x4;
typedef __attribute__((ext_vector_type(8))) __bf16 bf16x8;
typedef __attribute__((ext_vector_type(8))) _Float16 f16x8;

// bijective XCD swizzle (m204)
__device__ __forceinline__ int xcd_swz(int id, int nwg) {
  int q = nwg >> 3, r = nwg & 7;
  int xcd = id & 7, idx = id >> 3;
  return (xcd < r ? xcd * (q + 1) : r * (q + 1) + (xcd - r) * q) + idx;
}

// group id / timestep from flat sequence index
__device__ __forceinline__ void gid_ts(int i, int& g, int& t) {
  if (i < NTT) { g = 0; t = -1; }
  else {
    int j = i - NTT;
    t = j / PTT;
    int r = j - t * PTT;
    g = (r < NPP) ? 1 : ((r < NPP + NWW) ? 2 : 3);
  }
}

// ========== bf16 MFMA GEMM, 64x64 tile (ALL layer GEMMs + embeds) ==========
template<int ACT, int RES, int OUTBF, int QKVMODE>
__global__ __launch_bounds__(256) void gemm64_k(
    const bf16* __restrict__ A, const bf16* __restrict__ BT,
    const float* __restrict__ bias, const float* __restrict__ Rs,
    void* __restrict__ Cout, f16* __restrict__ VTg,
    int M, int N, int K)
{
  __shared__ bf16 Al[2][64 * 64];
  __shared__ bf16 Bl[2][64 * 64];
  const int tid = threadIdx.x;
  const int lane = tid & 63, w = tid >> 6;
  const int wr = w >> 1, wc = w & 1;
  int bxi, byi;
  {
    const int nwg = gridDim.x * gridDim.y;
    int swz = xcd_swz(blockIdx.y * gridDim.x + blockIdx.x, nwg);
    bxi = swz % gridDim.x; byi = swz / gridDim.x;
  }
  const int bm = byi * 64, bn = bxi * 64;
  const int r0 = lane & 15, kg4 = lane >> 4;
  f32x4 acc[2][2] = {};

  auto STAGE = [&](int s, int k0) {
    #pragma unroll
    for (int i = 0; i < 2; ++i) {
      int chunk = i * 256 + tid;           // 512 16B-chunks per operand tile
      int row = chunk >> 3, c8 = chunk & 7;
      const bf16* ga = A  + (size_t)(bm + row) * K + (k0 + c8 * 8);
      const bf16* gb = BT + (size_t)(bn + row) * K + (k0 + c8 * 8);
      __builtin_amdgcn_global_load_lds(
          (const __attribute__((address_space(1))) void*)ga,
          (__attribute__((address_space(3))) void*)((char*)Al[s] + chunk * 16), 16, 0, 0);
      __builtin_amdgcn_global_load_lds(
          (const __attribute__((address_space(1))) void*)gb,
          (__attribute__((address_space(3))) void*)((char*)Bl[s] + chunk * 16), 16, 0, 0);
    }
  };

  const int nt = K >> 6;
  STAGE(0, 0);
  __syncthreads();
  int cur = 0;
  for (int t = 0; t < nt; ++t) {
    if (t + 1 < nt) STAGE(cur ^ 1, (t + 1) << 6);   // prefetch next tile
    #pragma unroll
    for (int ks = 0; ks < 2; ++ks) {
      bf16x8 af[2], bfr[2];
      const int koff = ks * 32 + kg4 * 8;
      #pragma unroll
      for (int mi = 0; mi < 2; ++mi)
        af[mi] = *(const bf16x8*)((const void*)(Al[cur] + (wr * 32 + mi * 16 + r0) * 64 + koff));
      #pragma unroll
      for (int ni = 0; ni < 2; ++ni)
        bfr[ni] = *(const bf16x8*)((const void*)(Bl[cur] + (wc * 32 + ni * 16 + r0) * 64 + koff));
      #pragma unroll
      for (int mi = 0; mi < 2; ++mi)
        #pragma unroll
        for (int ni = 0; ni < 2; ++ni)
          acc[mi][ni] = __builtin_amdgcn_mfma_f32_16x16x32_bf16(af[mi], bfr[ni], acc[mi][ni], 0, 0, 0);
    }
    __syncthreads();
    cur ^= 1;
  }
  #pragma unroll
  for (int mi = 0; mi < 2; ++mi) {
    #pragma unroll
    for (int ni = 0; ni < 2; ++ni) {
      const int gcol = bn + wc * 32 + ni * 16 + r0;
      const float bv = bias[gcol];
      const int gr0 = bm + wr * 32 + mi * 16 + kg4 * 4;
      #pragma unroll
      for (int j = 0; j < 4; ++j) {
        const int gm = gr0 + j;
        if (gm >= M) continue;
        float vv = acc[mi][ni][j] + bv;
        if (ACT == 1) {
          float xx = vv;
          float th = tanhf(0.7978845608028654f * (xx + 0.044715f * xx * xx * xx));
          vv = 0.5f * xx * (1.f + th);
        }
        if (RES) vv += Rs[(size_t)gm * N + gcol];
        if (QKVMODE && gcol >= 1536) {
          const int vc = gcol - 1536;
          const int hh = vc >> 6, d = vc & 63;
          const int bb = gm >= SS;
          const int s = gm - bb * SS;
          VTg[(size_t)((bb * NHH + hh) * 64 + d) * SSP + s] = (f16)vv;
        } else if (OUTBF) {
          ((bf16*)Cout)[(size_t)gm * N + gcol] = __float2bfloat16(vv);
        } else {
          ((float*)Cout)[(size_t)gm * N + gcol] = vv;
        }
      }
    }
  }
}

// ---------------- LayerNorm (fp32 in, bf16 or f32 out) ----------------
template<int OUTBF>
__global__ __launch_bounds__(256) void ln2_k(
    const float* __restrict__ X, const float* __restrict__ sc,
    const float* __restrict__ bi, void* __restrict__ Y)
{
  const int row = blockIdx.x;
  const float* x = X + (size_t)row * DD;
  const int t = threadIdx.x;
  float v0 = x[t], v1 = x[t + 256], v2 = x[t + 512];
  float sum = v0 + v1 + v2;
  const int lane = t & 63, wid = t >> 6;
  __shared__ float rs[4];
  #pragma unroll
  for (int o = 32; o; o >>= 1) sum += __shfl_xor(sum, o);
  if (lane == 0) rs[wid] = sum;
  __syncthreads();
  float mean = (rs[0] + rs[1] + rs[2] + rs[3]) * (1.f / DD);
  __syncthreads();
  float d0 = v0 - mean, d1 = v1 - mean, d2 = v2 - mean;
  float sq = d0 * d0 + d1 * d1 + d2 * d2;
  #pragma unroll
  for (int o = 32; o; o >>= 1) sq += __shfl_xor(sq, o);
  if (lane == 0) rs[wid] = sq;
  __syncthreads();
  float var = (rs[0] + rs[1] + rs[2] + rs[3]) * (1.f / DD);
  float inv = rsqrtf(var + 1e-6f);
  float o0 = d0 * inv * sc[t] + bi[t];
  float o1 = d1 * inv * sc[t + 256] + bi[t + 256];
  float o2 = d2 * inv * sc[t + 512] + bi[t + 512];
  if (OUTBF) {
    bf16* y = (bf16*)Y + (size_t)row * DD;
    y[t] = __float2bfloat16(o0); y[t + 256] = __float2bfloat16(o1); y[t + 512] = __float2bfloat16(o2);
  } else {
    float* y = (float*)Y + (size_t)row * DD;
    y[t] = o0; y[t + 256] = o1; y[t + 512] = o2;
  }
}

// ================= MFMA flash attention =================
// Fast-path tiles: when a K-tile has no invalid keys, no readout columns, and
// lies fully inside every q-row's causal bound (kv0+64 <= kend of q-row 0,
// kend nondecreasing in q), the mask logic vanishes -> pure fma+exp2.
// exp2 fold: exp(s/8-2) = exp2(s*0.125*log2e - 2*log2e) saves a v_mul/elem.
__global__ __launch_bounds__(256) void mattn_k(
    const bf16* __restrict__ qkv, const f16* __restrict__ VTg,
    bf16* __restrict__ ao, const unsigned char* __restrict__ kflags,
    const unsigned char* __restrict__ tileok)
{
  __shared__ bf16 Kl[2][64 * 64];         // [ktok][dh], dh-chunks XOR-swizzled
  __shared__ f16  Vl[2][64 * 64];         // [d][kv], kv-chunks XOR-swizzled
  __shared__ unsigned short Pl[4][16][72];// per-wave P [q][k] fp16, pad 72
  __shared__ unsigned char Fl[2][64];
  const int tid = threadIdx.x;
  const int lane = tid & 63, w = tid >> 6;
  const int r0 = lane & 15, g = lane >> 4;
  int swz;
  {
    int id = blockIdx.x;
    swz = (id & 7) * 78 + (id >> 3);      // 624/8 = 78
  }
  const int qt = swz % 26;
  const int hb = swz / 26;
  const int h = hb % NHH, b = hb / NHH;

  const int q_my = qt * 64 + w * 16 + r0;     // this lane's q (S^T column)
  const int qc = min(q_my, SS - 1);
  int gq, tq; gid_ts(qc, gq, tq);
  const int kend = (tq < 0) ? NTT : NTT + (tq + 1) * PTT;
  const bool gq3 = (gq == 3);
  // block-uniform causal bound of q-row 0 (kend nondecreasing in q)
  int g0, t0; gid_ts(qt * 64, g0, t0);
  const int kend0 = (t0 < 0) ? NTT : NTT + (t0 + 1) * PTT;

  const int qlast = min(qt * 64 + 63, SS - 1);
  int gl, tl; gid_ts(qlast, gl, tl);
  const int kend_b = (tl < 0) ? NTT : NTT + (tl + 1) * PTT;
  const int ntiles = (kend_b + 63) >> 6;

  // Q fragments
  bf16x8 qf[2];
  {
    const bf16* qrow = qkv + (size_t)(b * SS + qc) * QKVN + h * DHH;
    qf[0] = *(const bf16x8*)((const void*)(qrow + g * 8));
    qf[1] = *(const bf16x8*)((const void*)(qrow + 32 + g * 8));
  }

  auto STAGE = [&](int s, int kt) {
    const int kv0 = kt * 64;
    #pragma unroll
    for (int i = 0; i < 2; ++i) {
      int c = i * 256 + tid;
      int row = c >> 3, blk = c & 7;
      int srow = min(kv0 + row, SS - 1);
      const bf16* srcK = qkv + (size_t)(b * SS + srow) * QKVN + DD + h * DHH + ((blk ^ (row & 7)) * 8);
      __builtin_amdgcn_global_load_lds(
          (const __attribute__((address_space(1))) void*)srcK,
          (__attribute__((address_space(3))) void*)((char*)Kl[s] + c * 16), 16, 0, 0);
      int kvs = kv0 + ((blk ^ (row & 7)) * 8);   // VTg pad cols [SS,SSP) zeroed
      const f16* srcV = VTg + (size_t)((b * NHH + h) * 64 + row) * SSP + kvs;
      __builtin_amdgcn_global_load_lds(
          (const __attribute__((address_space(1))) void*)srcV,
          (__attribute__((address_space(3))) void*)((char*)Vl[s] + c * 16), 16, 0, 0);
    }
    if (tid < 64) Fl[s][tid] = kflags[b * SS + min(kv0 + tid, SS - 1)];
  };

  f32x4 o_acc[4] = {};   // O C/D: col d = n*16+r0, row q = g*4+j
  float l_run = 0.f;
  const float S2 = 0.18033688011112042f;    // 0.125 * log2(e)
  const float C2 = -2.8853900817779268f;    // -2 * log2(e)
  const float CL = 14.426950408889634f;     // 10 * log2(e) clamp

  STAGE(0, 0);
  __syncthreads();
  int cur = 0;
  for (int kt = 0; kt < ntiles; ++kt) {
    const int kv0 = kt * 64;
    if (kt + 1 < ntiles) STAGE(cur ^ 1, kt + 1);   // prefetch next K/V tile

    // S^T = K @ Q^T
    f32x4 st[4] = {};
    __builtin_amdgcn_s_setprio(1);
    #pragma unroll
    for (int ks = 0; ks < 2; ++ks) {
      #pragma unroll
      for (int t = 0; t < 4; ++t) {
        const int krow = t * 16 + r0;
        const bf16x8 af = *(const bf16x8*)((const void*)(
            (char*)Kl[cur] + krow * 128 + ((ks * 64 + g * 16) ^ ((krow & 7) << 4))));
        st[t] = __builtin_amdgcn_mfma_f32_16x16x32_bf16(af, qf[ks], st[t], 0, 0, 0);
      }
    }
    __builtin_amdgcn_s_setprio(0);
    // mask + exp2 + write P fp16 (lane's q = r0 within wave)
    const bool fastp = tileok[b * NKT + kt] && (kv0 + 64 <= kend0);   // block-uniform
    if (fastp) {
      #pragma unroll
      for (int t = 0; t < 4; ++t) {
        unsigned short pk[4];
        #pragma unroll
        for (int r = 0; r < 4; ++r) {
          float ee = fminf(fmaf(st[t][r], S2, C2), CL);
          float pv = exp2f(ee);
          f16 hb2 = (f16)pv;
          l_run += (float)hb2;
          pk[r] = *(unsigned short*)&hb2;
        }
        uint2 pw;
        pw.x = (unsigned)pk[0] | ((unsigned)pk[1] << 16);
        pw.y = (unsigned)pk[2] | ((unsigned)pk[3] << 16);
        *(uint2*)((void*)&Pl[w][r0][t * 16 + g * 4]) = pw;
      }
    } else {
      #pragma unroll
      for (int t = 0; t < 4; ++t) {
        const unsigned fl4 = *(const unsigned*)((const void*)&Fl[cur][t * 16 + g * 4]);
        unsigned short pk[4];
        #pragma unroll
        for (int r = 0; r < 4; ++r) {
          const int kg_ = kv0 + t * 16 + g * 4 + r;
          const unsigned fb = (fl4 >> (8 * r)) & 0xffu;
          const bool ok = (kg_ < kend) && (fb & 1) && (gq3 || !(fb & 2));
          float ee = fminf(fmaf(st[t][r], S2, C2), CL);
          float pv = ok ? exp2f(ee) : 0.f;
          f16 hb2 = (f16)pv;
          l_run += (float)hb2;
          pk[r] = *(unsigned short*)&hb2;
        }
        uint2 pw;
        pw.x = (unsigned)pk[0] | ((unsigned)pk[1] << 16);
        pw.y = (unsigned)pk[2] | ((unsigned)pk[3] << 16);
        *(uint2*)((void*)&Pl[w][r0][t * 16 + g * 4]) = pw;
      }
    }
    // P ds_writes visible to own wave; keep prefetch vmcnt alive
    asm volatile("s_waitcnt lgkmcnt(0)" ::: "memory");
    __builtin_amdgcn_sched_barrier(0);
    // PV: O += P @ V
    __builtin_amdgcn_s_setprio(1);
    #pragma unroll
    for (int ks = 0; ks < 2; ++ks) {
      const f16x8 pa = *(const f16x8*)((const void*)(
          (char*)&Pl[w][r0][0] + ks * 64 + g * 16));
      #pragma unroll
      for (int n = 0; n < 4; ++n) {
        const int drow = n * 16 + r0;
        const f16x8 bv = *(const f16x8*)((const void*)(
            (char*)Vl[cur] + drow * 128 + ((ks * 64 + g * 16) ^ ((drow & 7) << 4))));
        o_acc[n] = __builtin_amdgcn_mfma_f32_16x16x32_f16(pa, bv, o_acc[n], 0, 0, 0);
      }
    }
    __builtin_amdgcn_s_setprio(0);
    __syncthreads();
    cur ^= 1;
  }
  // denominator
  float lt = l_run;
  lt += __shfl_xor(lt, 16);
  lt += __shfl_xor(lt, 32);
  const float inv = 1.f / lt;
  float invr[4];
  #pragma unroll
  for (int j = 0; j < 4; ++j) invr[j] = __shfl(inv, g * 4 + j);
  #pragma unroll
  for (int n = 0; n < 4; ++n) {
    const int d = n * 16 + r0;
    #pragma unroll
    for (int j = 0; j < 4; ++j) {
      const int q = qt * 64 + w * 16 + g * 4 + j;
      if (q < SS)
        ao[(size_t)(b * SS + q) * DD + h * DHH + d] = __float2bfloat16(o_acc[n][j] * invr[j]);
    }
  }
}

// ---------------- token assembly ----------------
__global__ __launch_bounds__(256) void assemble_k(
    const float* __restrict__ tE, const float* __restrict__ pE, const float* __restrict__ wE,
    const float* __restrict__ posT, const float* __restrict__ posP,
    const float* __restrict__ posW, const float* __restrict__ posR,
    float* __restrict__ X)
{
  const int row = blockIdx.x;
  const int b = row / SS, s = row - b * SS;
  float* x = X + (size_t)row * DD;
  const float* src; const float* pos;
  if (s < NTT) { src = tE + (size_t)(b * NTT + s) * DD; pos = posT + (size_t)s * DD; }
  else {
    int j = s - NTT, t = j / PTT, r = j - t * PTT;
    if (r < NPP)            { src = pE + (size_t)((b * Hh + t) * NPP + r) * DD;
                              pos = posP + (size_t)(t * NPP + r) * DD; }
    else if (r < NPP + NWW) { src = wE + (size_t)((b * Hh + t) * NWW + (r - NPP)) * DD;
                              pos = posW + (size_t)(t * NWW + (r - NPP)) * DD; }
    else                    { src = nullptr; pos = posR + (size_t)t * DD; }
  }
  for (int d = threadIdx.x; d < DD; d += 256)
    x[d] = (src ? src[d] : 0.f) + pos[d];
}

// key flags: bit0 = key valid (pad_mask), bit1 = is readout column
__global__ void build_kv_k(const void* pm, unsigned char* kvout) {
  int i = blockIdx.x * 256 + threadIdx.x;
  if (i >= Bb * SS) return;
  int b = i / SS, s = i - b * SS;
  int g, t; gid_ts(s, g, t);
  unsigned char valid = 1;
  if (g == 1 || g == 2) {
    int idx = b * Hh + t;
    unsigned char c = ((const unsigned char*)pm)[idx];
    int ii = ((const int*)pm)[idx];
    valid = (c != 0 || ii != 0) ? 1 : 0;
  }
  kvout[i] = valid | ((g == 3) ? 2 : 0);
}

// tile_ok[b][kt]: K-tile fully valid & free of readout columns
__global__ void tileok_k(const unsigned char* __restrict__ kv, unsigned char* __restrict__ tok) {
  int i = threadIdx.x;
  if (i >= Bb * NKT) return;
  int b = i / NKT, kt = i % NKT;
  unsigned char ok = 1;
  for (int s = kt * 64; s < min(kt * 64 + 64, SS); ++s) {
    unsigned char f = kv[b * SS + s];
    if (!(f & 1) || (f & 2)) { ok = 0; break; }
  }
  if (kt * 64 + 64 > SS) ok = 0;   // tail tile: never fast
  tok[i] = ok;
}

// zero a buffer (16B granules)
__global__ void zset_k(ushort4* p, int n16) {
  int i = blockIdx.x * 256 + threadIdx.x;
  if (i < n16) { ushort4 z = {0, 0, 0, 0}; p[i] = z; }
}

// ---- embed weight transpose+convert ----
__global__ __launch_bounds__(256) void eprep_k(
    const float* __restrict__ Wt, const float* __restrict__ Wp, const float* __restrict__ Ww,
    bf16* __restrict__ ET)
{
  const int bid = blockIdx.x;          // 3 * 16 * 24 = 1152
  const int sel = bid / 384, rem = bid % 384;
  const int a = rem / 24, bcol = rem % 24;
  const float* src = sel == 0 ? Wt : (sel == 1 ? Wp : Ww);
  bf16* dst = ET + (size_t)sel * 768 * 512;
  __shared__ float t[32][33];
  const int ib = threadIdx.x >> 5, j = threadIdx.x & 31;
  #pragma unroll
  for (int rr = 0; rr < 4; ++rr) {
    int i = ib + rr * 8;
    t[i][j] = src[(size_t)(a * 32 + i) * 768 + bcol * 32 + j];
  }
  __syncthreads();
  #pragma unroll
  for (int rr = 0; rr < 4; ++rr) {
    int i = ib + rr * 8;
    dst[(size_t)(bcol * 32 + i) * 512 + a * 32 + j] = __float2bfloat16(t[j][i]);
  }
}

// ---- convert embed inputs f32 -> bf16 rows [EROWS][512] ----
__global__ void cvtA_k(const float* __restrict__ t, const float* __restrict__ p,
                       const float* __restrict__ w, bf16* __restrict__ out)
{
  int i = blockIdx.x * 256 + threadIdx.x;
  const int total4 = EROWS * 512 / 4;
  if (i >= total4) return;
  int e = i * 4;
  const float* src; int off;
  if (e < 32 * 512)        { src = t; off = e; }
  else if (e < 2592 * 512) { src = p; off = e - 32 * 512; }
  else                     { src = w; off = e - 2592 * 512; }
  float4 v = *(const float4*)(src + off);
  bf16* o = out + e;
  o[0] = __float2bfloat16(v.x); o[1] = __float2bfloat16(v.y);
  o[2] = __float2bfloat16(v.z); o[3] = __float2bfloat16(v.w);
}

// ---- ALL layers weight transpose+convert, one launch, 64x64 tiles ----
__global__ __launch_bounds__(256) void prep12_k(
    const float* __restrict__ Wq, const float* __restrict__ Wk, const float* __restrict__ Wv,
    const float* __restrict__ Wo, const float* __restrict__ W1, const float* __restrict__ W2,
    bf16* __restrict__ QKVT, bf16* __restrict__ OT,
    bf16* __restrict__ W1T, bf16* __restrict__ W2T,
    const float* __restrict__ bq_, const float* __restrict__ bk_,
    const float* __restrict__ bv_, float* __restrict__ bqkv)
{
  const int l = blockIdx.x / 1729;
  const int bid = blockIdx.x % 1729;
  if (bid == 1728) {
    int i = threadIdx.x;
    for (; i < QKVN; i += 256) {
      float v = (i < DD) ? bq_[l * DD + i]
              : ((i < 2 * DD) ? bk_[l * DD + i - DD] : bv_[l * DD + i - 2 * DD]);
      bqkv[l * QKVN + i] = v;
    }
    return;
  }
  __shared__ float t[64][65];
  const float* src; bf16* dst;
  int a, bcol, R, C, dbase;
  if (bid < 432)       { int sel = bid / 144, rem = bid % 144; a = rem / 12; bcol = rem % 12;
                         src = (sel == 0 ? Wq : (sel == 1 ? Wk : Wv)) + (size_t)l * DD * DD;
                         dst = QKVT + (size_t)l * QKVN * DD; R = 768; C = 768; dbase = sel * 768; }
  else if (bid < 576)  { int rem = bid - 432; a = rem / 12; bcol = rem % 12;
                         src = Wo + (size_t)l * DD * DD; dst = OT + (size_t)l * DD * DD;
                         R = 768; C = 768; dbase = 0; }
  else if (bid < 1152) { int rem = bid - 576; a = rem / 48; bcol = rem % 48;
                         src = W1 + (size_t)l * DD * DFF; dst = W1T + (size_t)l * DFF * DD;
                         R = 768; C = 3072; dbase = 0; }
  else                 { int rem = bid - 1152; a = rem / 12; bcol = rem % 12;
                         src = W2 + (size_t)l * DFF * DD; dst = W2T + (size_t)l * DD * DFF;
                         R = 3072; C = 768; dbase = 0; }
  const int ib = threadIdx.x >> 6, j = threadIdx.x & 63;
  #pragma unroll
  for (int rr = 0; rr < 16; ++rr) {
    int i = rr * 4 + ib;
    t[i][j] = src[(size_t)(a * 64 + i) * C + bcol * 64 + j];
  }
  __syncthreads();
  #pragma unroll
  for (int rr = 0; rr < 16; ++rr) {
    int i = rr * 4 + ib;
    dst[(size_t)(dbase + bcol * 64 + i) * R + a * 64 + j] = __float2bfloat16(t[j][i]);
  }
}

extern "C" void kernel_launch(void* const* d_in, const int* in_sizes, int n_in,
                              void* d_out, int out_size, void* d_ws, size_t ws_size,
                              hipStream_t stream)
{
  const float* task_tokens = (const float*)d_in[0];
  const float* obs_primary = (const float*)d_in[1];
  const float* obs_wrist   = (const float*)d_in[2];
  const float* W_task      = (const float*)d_in[3];
  const float* b_task      = (const float*)d_in[4];
  const float* W_primary   = (const float*)d_in[5];
  const float* b_primary   = (const float*)d_in[6];
  const float* W_wrist     = (const float*)d_in[7];
  const float* b_wrist     = (const float*)d_in[8];
  const float* pos_task    = (const float*)d_in[9];
  const float* pos_primary = (const float*)d_in[10];
  const float* pos_wrist   = (const float*)d_in[11];
  const float* pos_readout = (const float*)d_in[12];
  const float* ln1_s = (const float*)d_in[13];
  const float* ln1_b = (const float*)d_in[14];
  const float* Wq = (const float*)d_in[15];
  const float* bq = (const float*)d_in[16];
  const float* Wk = (const float*)d_in[17];
  const float* bk = (const float*)d_in[18];
  const float* Wv = (const float*)d_in[19];
  const float* bv = (const float*)d_in[20];
  const float* Wo = (const float*)d_in[21];
  const float* bo = (const float*)d_in[22];
  const float* ln2_s = (const float*)d_in[23];
  const float* ln2_b = (const float*)d_in[24];
  const float* W1 = (const float*)d_in[25];
  const float* b1 = (const float*)d_in[26];
  const float* W2 = (const float*)d_in[27];
  const float* b2 = (const float*)d_in[28];
  const float* lnf_s = (const float*)d_in[29];
  const float* lnf_b = (const float*)d_in[30];
  const void*  pad_mask = d_in[31];

  // ---- workspace layout ----
  char* p = (char*)d_ws;
  auto alloc = [&](size_t bytes) { char* r = p; p += (bytes + 255) & ~(size_t)255; return r; };
  float* x    = (float*)alloc((size_t)MPAD * DD * 4);
  bf16*  y    = (bf16*) alloc((size_t)MPAD * DD * 2);
  bf16*  qkv  = (bf16*) alloc((size_t)MPAD * QKVN * 2);
  bf16*  ao   = (bf16*) alloc((size_t)MPAD * DD * 2);
  f16*   VTg  = (f16*)  alloc((size_t)Bb * NHH * 64 * SSP * 2);
  bf16*  QKVT = (bf16*) alloc((size_t)LL * QKVN * DD * 2);
  bf16*  OT   = (bf16*) alloc((size_t)LL * DD * DD * 2);
  bf16*  W1T  = (bf16*) alloc((size_t)LL * DFF * DD * 2);
  bf16*  W2T  = (bf16*) alloc((size_t)LL * DD * DFF * 2);
  bf16*  ET   = (bf16*) alloc((size_t)3 * DD * DINN * 2);
  bf16*  abf  = (bf16*) alloc((size_t)EROWS * DINN * 2);
  float* bqkv = (float*)alloc((size_t)LL * QKVN * 4);
  unsigned char* keyv = (unsigned char*)alloc(Bb * SS);
  unsigned char* tok  = (unsigned char*)alloc(Bb * NKT);
  // union region: {h1} | {te,pe,we}
  char* uni = alloc((size_t)MPAD * DFF * 2);
  bf16*  h1   = (bf16*)uni;
  float* te   = (float*)uni;
  float* pe   = te + (size_t)Bb * NTT * DD;
  float* we   = pe + (size_t)Bb * Hh * NPP * DD;

  // --- one-time setup ---
  {
    int n16 = (int)((size_t)Bb * NHH * 64 * SSP * 2 / 16);
    zset_k<<<dim3((n16 + 255) / 256), 256, 0, stream>>>((ushort4*)VTg, n16);
  }
  prep12_k<<<LL * 1729, 256, 0, stream>>>(Wq, Wk, Wv, Wo, W1, W2,
                                          QKVT, OT, W1T, W2T, bq, bk, bv, bqkv);
  eprep_k<<<1152, 256, 0, stream>>>(W_task, W_primary, W_wrist, ET);
  cvtA_k<<<dim3((EROWS * 512 / 4 + 255) / 256), 256, 0, stream>>>(
      task_tokens, obs_primary, obs_wrist, abf);
  gemm64_k<0, 0, 0, 0><<<dim3(12, 1),  256, 0, stream>>>(
      abf,               ET,                 b_task,    nullptr, te, nullptr, 32,   DD, DINN);
  gemm64_k<0, 0, 0, 0><<<dim3(12, 40), 256, 0, stream>>>(
      abf + 32 * DINN,   ET + DD * DINN,     b_primary, nullptr, pe, nullptr, 2560, DD, DINN);
  gemm64_k<0, 0, 0, 0><<<dim3(12, 10), 256, 0, stream>>>(
      abf + 2592 * DINN, ET + 2 * DD * DINN, b_wrist,   nullptr, we, nullptr, 640,  DD, DINN);
  assemble_k<<<dim3(MM), 256, 0, stream>>>(te, pe, we, pos_task, pos_primary, pos_wrist, pos_readout, x);
  build_kv_k<<<dim3((Bb * SS + 255) / 256), 256, 0, stream>>>(pad_mask, keyv);
  tileok_k<<<1, 64, 0, stream>>>(keyv, tok);

  // --- transformer layers ---
  for (int l = 0; l < LL; ++l) {
    ln2_k<1><<<MM, 256, 0, stream>>>(x, ln1_s + l * DD, ln1_b + l * DD, y);
    gemm64_k<0, 0, 1, 1><<<dim3(QKVN / 64, MPAD / 64), 256, 0, stream>>>(
        y, QKVT + (size_t)l * QKVN * DD, bqkv + l * QKVN, nullptr, qkv, VTg, MM, QKVN, DD);
    mattn_k<<<dim3(26 * NHH * Bb), 256, 0, stream>>>(qkv, VTg, ao, keyv, tok);
    gemm64_k<0, 1, 0, 0><<<dim3(DD / 64, MPAD / 64), 256, 0, stream>>>(
        ao, OT + (size_t)l * DD * DD, bo + l * DD, x, x, nullptr, MM, DD, DD);
    ln2_k<1><<<MM, 256, 0, stream>>>(x, ln2_s + l * DD, ln2_b + l * DD, y);
    gemm64_k<1, 0, 1, 0><<<dim3(DFF / 64, MPAD / 64), 256, 0, stream>>>(
        y, W1T + (size_t)l * DFF * DD, b1 + l * DFF, nullptr, h1, nullptr, MM, DFF, DD);
    gemm64_k<0, 1, 0, 0><<<dim3(DD / 64, MPAD / 64), 256, 0, stream>>>(
        h1, W2T + (size_t)l * DD * DFF, b2 + l * DD, x, x, nullptr, MM, DD, DFF);
  }
  // --- final LN -> d_out ---
  ln2_k<0><<<MM, 256, 0, stream>>>(x, lnf_s, lnf_b, d_out);
}